// Round 6
// baseline (483.163 us; speedup 1.0000x reference)
//
#include <hip/hip_runtime.h>

typedef unsigned short u16;
typedef unsigned int u32;
typedef __attribute__((ext_vector_type(8))) short short8v;
typedef __attribute__((ext_vector_type(4))) float float4v;
typedef __attribute__((ext_vector_type(4))) int   int4v;

#define N_NODES 8192
#define D_IN    512
#define D_OUT   128
#define SLOPEF  0.2f
#define LOG2E   1.4426950408889634f
#define NSEG    4
#define SEGCOLS 2048   // N_NODES / NSEG
#define NCHUNK  8      // SEGCOLS / 256

static __device__ __forceinline__ u16 f2bf(float f) {
    union { float f; unsigned int i; } v; v.f = f;
    unsigned int r = v.i + 0x7fff + ((v.i >> 16) & 1);
    return (u16)(r >> 16);
}
static __device__ __forceinline__ void lds_barrier() {
    asm volatile("s_waitcnt lgkmcnt(0)" ::: "memory");
    __builtin_amdgcn_s_barrier();
    asm volatile("" ::: "memory");
}

// ---------------- Kernel B: bitpack adj (256 MB -> 8 MB), 16 B/lane streaming ----------------
// No ballots: each lane owns 32 consecutive adj words (128 B via 8x dwordx4) and packs
// its own u32 with lshl_or (adj values are exactly 0/1). Output = standard col-order bits.
// Two far-apart tasks per thread -> 16 independent 16B loads in flight per lane.
__global__ __launch_bounds__(256) void kb_pack(
        const int* __restrict__ adj, u32* __restrict__ mask32)
{
    const size_t gid = (size_t)blockIdx.x * 256 + threadIdx.x;   // 0..1048575
    const size_t HALF = 1048576;                                  // tasks per half
    const int4v* p0 = (const int4v*)(adj + gid * 32);
    const int4v* p1 = (const int4v*)(adj + (gid + HALF) * 32);
    int4v v0[8], v1[8];
    #pragma unroll
    for (int k = 0; k < 8; k++) v0[k] = p0[k];
    #pragma unroll
    for (int k = 0; k < 8; k++) v1[k] = p1[k];
    u32 m0 = 0, m1 = 0;
    #pragma unroll
    for (int k = 0; k < 8; k++) {
        #pragma unroll
        for (int e = 0; e < 4; e++) {
            m0 |= ((u32)v0[k][e]) << (k * 4 + e);   // adj in {0,1}
            m1 |= ((u32)v1[k][e]) << (k * 4 + e);
        }
    }
    mask32[gid] = m0;
    mask32[gid + HALF] = m1;
}

// ---------------- Kernel 1: Wh = h@W (fp32 in), WhT bf16 [128][8192], f1, f2 (x log2e) ----------------
__global__ __launch_bounds__(256, 2) void k1_proj(
        const float* __restrict__ h, const float* __restrict__ W,
        const float* __restrict__ a, u16* __restrict__ WhT,
        float* __restrict__ f1, float* __restrict__ f2)
{
    __shared__ float hs[16 * D_IN];     // 32 KB
    __shared__ float buf[16 * 128];     // 8 KB
    __shared__ float part[16][17];
    const int tid = threadIdx.x;
    const int rowbase = blockIdx.x * 16;

    const float4v* hsrc = (const float4v*)(h + (size_t)rowbase * D_IN);
    #pragma unroll
    for (int i = 0; i < 8; i++) {
        *(float4v*)&hs[(tid + 256 * i) * 4] = hsrc[tid + 256 * i];
    }
    __syncthreads();

    const int c  = tid & 127;   // output feature
    const int rh = tid >> 7;    // row half (8 rows each)
    float acc[8];
    #pragma unroll
    for (int rr = 0; rr < 8; rr++) acc[rr] = 0.f;

    for (int k = 0; k < D_IN; k += 4) {
        float wv[4];
        #pragma unroll
        for (int kk = 0; kk < 4; kk++) wv[kk] = W[(k + kk) * D_OUT + c];
        #pragma unroll
        for (int rr = 0; rr < 8; rr++) {
            float4v hv = *(const float4v*)&hs[(rh * 8 + rr) * D_IN + k];
            acc[rr] += hv[0] * wv[0];
            acc[rr] += hv[1] * wv[1];
            acc[rr] += hv[2] * wv[2];
            acc[rr] += hv[3] * wv[3];
        }
    }

    {
        short8v pack;
        #pragma unroll
        for (int rr = 0; rr < 8; rr++) pack[rr] = (short)f2bf(acc[rr]);
        *(short8v*)(WhT + (size_t)c * N_NODES + rowbase + rh * 8) = pack;
    }

    const float a1 = a[c];
    const float a2 = a[D_OUT + c];

    #pragma unroll
    for (int rr = 0; rr < 8; rr++) buf[(rh * 8 + rr) * 128 + c] = acc[rr] * a1;
    __syncthreads();
    {
        const int row = tid >> 4, seg = tid & 15;
        float p = 0.f;
        #pragma unroll
        for (int e = 0; e < 8; e++) p += buf[row * 128 + seg * 8 + e];
        part[row][seg] = p;
    }
    __syncthreads();
    if (tid < 16) {
        float s = 0.f;
        #pragma unroll
        for (int j = 0; j < 16; j++) s += part[tid][j];
        f1[rowbase + tid] = s * LOG2E;       // pre-scaled for exp2
    }
    __syncthreads();
    #pragma unroll
    for (int rr = 0; rr < 8; rr++) buf[(rh * 8 + rr) * 128 + c] = acc[rr] * a2;
    __syncthreads();
    {
        const int row = tid >> 4, seg = tid & 15;
        float p = 0.f;
        #pragma unroll
        for (int e = 0; e < 8; e++) p += buf[row * 128 + seg * 8 + e];
        part[row][seg] = p;
    }
    __syncthreads();
    if (tid < 16) {
        float s = 0.f;
        #pragma unroll
        for (int j = 0; j < 16; j++) s += part[tid][j];
        f2[rowbase + tid] = s * LOG2E;       // pre-scaled for exp2
    }
}

// ---------------- Kernel 2: fused mask+exp2 + partial PV via MFMA (bitmask input) ----------------
// Block = 32 rows x 2048-col segment. Thread (r,g) owns 32 consecutive cols per 256-chunk.
__global__ __launch_bounds__(256, 4) void k2_attn(
        const u32* __restrict__ mask, const u16* __restrict__ WhT,
        const float* __restrict__ f1g, const float* __restrict__ f2g,
        float* __restrict__ numw, float* __restrict__ denw)
{
    __shared__ short Pt[32 * 264];       // 16.9 KB, row stride 264 shorts
    __shared__ float f2s[2304];          // 2048 + 4-float pad per 32 -> bank-spread
    __shared__ float f1s[32];
    __shared__ float rs[32][9];
    __shared__ float ssum[32];

    const int tid = threadIdx.x;
    const int rb  = blockIdx.x >> 2;
    const int seg = blockIdx.x & 3;
    const int rowbase = rb * 32;
    const int colbase = seg * SEGCOLS;
    const int r = tid >> 3, g = tid & 7;
    const int lane = tid & 63, w = tid >> 6;
    const int quad = lane >> 4, m16 = lane & 15;

    if (tid < 32) f1s[tid] = f1g[rowbase + tid];
    #pragma unroll
    for (int i = 0; i < 2; i++) {
        const int idx = (tid + 256 * i) * 4;
        *(float4v*)&f2s[idx + ((idx >> 5) << 2)] = *(const float4v*)&f2g[colbase + idx];
    }

    const u32* mrow = mask + (size_t)(rowbase + r) * (N_NODES / 32) + seg * (SEGCOLS / 32);
    u32 mcur = mrow[g];    // chunk 0 word: cols g*32..g*32+31

    float4v acc[2][2];
    #pragma unroll
    for (int mt = 0; mt < 2; mt++)
        #pragma unroll
        for (int nt = 0; nt < 2; nt++) {
            acc[mt][nt][0] = 0.f; acc[mt][nt][1] = 0.f;
            acc[mt][nt][2] = 0.f; acc[mt][nt][3] = 0.f;
        }
    float ls0 = 0.f, ls1 = 0.f, ls2 = 0.f, ls3 = 0.f;

    __syncthreads();   // f1s/f2s ready

    for (int jc = 0; jc < NCHUNK; jc++) {
        u32 mnext = 0;
        if (jc + 1 < NCHUNK) mnext = mrow[(jc + 1) * 8 + g];

        // ---- weight phase: 32 consecutive cols per thread ----
        const float f1v = f1s[r];
        const float* f2p = &f2s[jc * 288 + g * 36];
        u32 packed[16];
        #pragma unroll
        for (int i = 0; i < 8; i++) {
            const float4v fv = *(const float4v*)&f2p[i * 4];
            u32 wb[4];
            #pragma unroll
            for (int e = 0; e < 4; e++) {
                const int idx = i * 4 + e;
                const int sel = ((int)(mcur << (31 - idx))) >> 31;   // 0 or -1
                float x = f1v + fv[e];
                x = fmaxf(x, SLOPEF * x);                            // leaky_relu (log2 domain)
                const float ex = __builtin_amdgcn_exp2f(x);
                const u32 wt = __float_as_uint(ex) & ((u32)sel & 0xffff0000u); // masked + bf16-trunc
                wb[e] = wt;
                if (e == 0) ls0 += __uint_as_float(wt);
                else if (e == 1) ls1 += __uint_as_float(wt);
                else if (e == 2) ls2 += __uint_as_float(wt);
                else ls3 += __uint_as_float(wt);
            }
            packed[i * 2]     = __builtin_amdgcn_perm(wb[1], wb[0], 0x07060302);
            packed[i * 2 + 1] = __builtin_amdgcn_perm(wb[3], wb[2], 0x07060302);
        }
        {
            int* pdst = (int*)&Pt[r * 264 + g * 32];
            #pragma unroll
            for (int q = 0; q < 4; q++) {
                int4v st;
                st[0] = (int)packed[q * 4 + 0]; st[1] = (int)packed[q * 4 + 1];
                st[2] = (int)packed[q * 4 + 2]; st[3] = (int)packed[q * 4 + 3];
                *(int4v*)&pdst[q * 4] = st;
            }
        }
        mcur = mnext;
        lds_barrier();

        // ---- MFMA phase: acc += P[32 x 256] @ Wh[256 x 128] (this wave's 32 feature cols) ----
        {
            const u16* b0p = WhT + (size_t)(w * 32 + m16) * N_NODES + colbase + jc * 256 + quad * 8;
            const u16* b1p = b0p + 16 * N_NODES;
            const short* a0p = &Pt[m16 * 264 + quad * 8];
            const short* a1p = a0p + 16 * 264;
            #pragma unroll
            for (int ks = 0; ks < 8; ks++) {
                const int ko = ks * 32;
                const short8v af0 = *(const short8v*)(a0p + ko);
                const short8v af1 = *(const short8v*)(a1p + ko);
                const short8v bv0 = *(const short8v*)(b0p + ko);
                const short8v bv1 = *(const short8v*)(b1p + ko);
                acc[0][0] = __builtin_amdgcn_mfma_f32_16x16x32_bf16(af0, bv0, acc[0][0], 0, 0, 0);
                acc[0][1] = __builtin_amdgcn_mfma_f32_16x16x32_bf16(af0, bv1, acc[0][1], 0, 0, 0);
                acc[1][0] = __builtin_amdgcn_mfma_f32_16x16x32_bf16(af1, bv0, acc[1][0], 0, 0, 0);
                acc[1][1] = __builtin_amdgcn_mfma_f32_16x16x32_bf16(af1, bv1, acc[1][1], 0, 0, 0);
            }
        }
        lds_barrier();
    }

    // per-row partial denominator
    rs[r][g] = (ls0 + ls1) + (ls2 + ls3);
    __syncthreads();
    if (tid < 32) {
        float s = 0.f;
        #pragma unroll
        for (int j = 0; j < 8; j++) s += rs[tid][j];
        ssum[tid] = s;
        denw[(size_t)(rowbase + tid) * NSEG + seg] = s;
    }
    __syncthreads();

    // epilogue: write partial numerator. C/D layout col=lane&15, row=quad*4+reg
    #pragma unroll
    for (int mt = 0; mt < 2; mt++) {
        #pragma unroll
        for (int nt = 0; nt < 2; nt++) {
            const int cl = w * 32 + nt * 16 + m16;
            #pragma unroll
            for (int reg = 0; reg < 4; reg++) {
                const int rl = mt * 16 + quad * 4 + reg;
                numw[((size_t)(rowbase + rl) * NSEG + seg) * D_OUT + cl] = acc[mt][nt][reg];
            }
        }
    }
}

// ---------------- Kernel 3: reduce partials, divide, write output ----------------
__global__ __launch_bounds__(256) void k3_reduce(
        const float* __restrict__ numw, const float* __restrict__ denw,
        float* __restrict__ out)
{
    const int tid = threadIdx.x;
    const int row = blockIdx.x * 2 + (tid >> 7);
    const int c   = tid & 127;
    float s = 0.f, d = 0.f;
    #pragma unroll
    for (int sg = 0; sg < NSEG; sg++) {
        s += numw[((size_t)row * NSEG + sg) * D_OUT + c];
        d += denw[(size_t)row * NSEG + sg];
    }
    out[(size_t)row * D_OUT + c] = s / d;
}

extern "C" void kernel_launch(void* const* d_in, const int* in_sizes, int n_in,
                              void* d_out, int out_size, void* d_ws, size_t ws_size,
                              hipStream_t stream) {
    const float* h   = (const float*)d_in[0];
    const int*   adj = (const int*)d_in[1];
    const float* W   = (const float*)d_in[2];
    const float* a   = (const float*)d_in[3];

    char* ws = (char*)d_ws;
    u32*   mask32 = (u32*)ws;                                  // 8 MB
    u16*   WhT = (u16*)(ws + (size_t)8 * 1024 * 1024);         // 2 MB
    float* f1  = (float*)(ws + (size_t)10 * 1024 * 1024);      // 32 KB
    float* f2  = f1 + N_NODES;                                 // 32 KB
    float* numw = (float*)(ws + (size_t)12 * 1024 * 1024);     // 16 MB
    float* denw = (float*)(ws + (size_t)28 * 1024 * 1024);     // 128 KB

    kb_pack<<<4096, 256, 0, stream>>>(adj, mask32);
    k1_proj<<<N_NODES / 16, 256, 0, stream>>>(h, W, a, WhT, f1, f2);
    k2_attn<<<(N_NODES / 32) * NSEG, 256, 0, stream>>>(mask32, WhT, f1, f2, numw, denw);
    k3_reduce<<<N_NODES / 2, 256, 0, stream>>>(numw, denw, (float*)d_out);
}

// Round 8
// 420.079 us; speedup vs baseline: 1.1502x; 1.1502x over previous
//
#include <hip/hip_runtime.h>

typedef unsigned short u16;
typedef unsigned int u32;
typedef __attribute__((ext_vector_type(8))) short short8v;
typedef __attribute__((ext_vector_type(4))) short short4v;
typedef __attribute__((ext_vector_type(4))) float float4v;
typedef __attribute__((ext_vector_type(4))) int   int4v;

#define N_NODES 8192
#define D_IN    512
#define D_OUT   128
#define SLOPEF  0.2f
#define LOG2E   1.4426950408889634f
#define NSEG    4
#define SEGCOLS 2048   // N_NODES / NSEG
#define NCHUNK  8      // SEGCOLS / 256

static __device__ __forceinline__ u16 f2bf(float f) {
    union { float f; unsigned int i; } v; v.f = f;
    unsigned int r = v.i + 0x7fff + ((v.i >> 16) & 1);
    return (u16)(r >> 16);
}
static __device__ __forceinline__ void lds_barrier() {
    asm volatile("s_waitcnt lgkmcnt(0)" ::: "memory");
    __builtin_amdgcn_s_barrier();
    asm volatile("" ::: "memory");
}

// ---------------- Kernel C: fp32 -> bf16 convert (h -> hb row-major, W -> WbT [n][k]) --------
__global__ __launch_bounds__(256) void kc_convert(
        const float* __restrict__ h, const float* __restrict__ W,
        u16* __restrict__ hb, u16* __restrict__ WbT)
{
    if (blockIdx.x < 2048) {
        const size_t t = (size_t)blockIdx.x * 256 + threadIdx.x;   // 524288 threads x 8 elems
        const float4v* src = (const float4v*)h + t * 2;
        const float4v v0 = src[0], v1 = src[1];
        short8v o;
        o[0] = (short)f2bf(v0[0]); o[1] = (short)f2bf(v0[1]);
        o[2] = (short)f2bf(v0[2]); o[3] = (short)f2bf(v0[3]);
        o[4] = (short)f2bf(v1[0]); o[5] = (short)f2bf(v1[1]);
        o[6] = (short)f2bf(v1[2]); o[7] = (short)f2bf(v1[3]);
        *(short8v*)(hb + t * 8) = o;
    } else {
        const int t2 = (blockIdx.x - 2048) * 256 + threadIdx.x;    // 0..8191
        const int k = t2 >> 4;            // 512 k values
        const int n0 = (t2 & 15) * 8;     // 8 consecutive n
        const float4v* src = (const float4v*)(W + (size_t)k * D_OUT + n0);
        const float4v v0 = src[0], v1 = src[1];
        #pragma unroll
        for (int e = 0; e < 4; e++) WbT[(size_t)(n0 + e) * D_IN + k] = f2bf(v0[e]);
        #pragma unroll
        for (int e = 0; e < 4; e++) WbT[(size_t)(n0 + 4 + e) * D_IN + k] = f2bf(v1[e]);
    }
}

// ---------------- Kernel 1M: Wh = h@W via MFMA; WhT bf16 [128][8192]; f1,f2 (x log2e) --------
// Block: 32 rows x 128 cols, K=512 in 4 chunks of 128. Grid 256.
__global__ __launch_bounds__(256) void k1m_proj(
        const u16* __restrict__ hb, const u16* __restrict__ WbT,
        const float* __restrict__ a, u16* __restrict__ WhT,
        float* __restrict__ f1, float* __restrict__ f2)
{
    __shared__ short As[32 * 136];     // 8.5 KB, stride 136 shorts
    __shared__ short Ws[128 * 136];    // 34 KB
    __shared__ float pf1[32][65];      // 8.3 KB
    __shared__ float pf2[32][65];      // 8.3 KB

    const int tid = threadIdx.x;
    const int rowbase = blockIdx.x * 32;
    const int lane = tid & 63, w = tid >> 6;
    const int quad = lane >> 4, m16 = lane & 15;

    float4v acc[2][2];
    #pragma unroll
    for (int mt = 0; mt < 2; mt++)
        #pragma unroll
        for (int nt = 0; nt < 2; nt++) {
            acc[mt][nt][0] = 0.f; acc[mt][nt][1] = 0.f;
            acc[mt][nt][2] = 0.f; acc[mt][nt][3] = 0.f;
        }

    for (int c = 0; c < 4; c++) {
        const int kc0 = c * 128;
        if (c) __syncthreads();   // prev chunk's LDS reads done
        // stage A: 32 rows x 128 k
        {
            const int row = tid >> 3, koff = (tid & 7) * 16;
            const short8v* src = (const short8v*)(hb + (size_t)(rowbase + row) * D_IN + kc0 + koff);
            const short8v s0 = src[0], s1 = src[1];
            *(short8v*)&As[row * 136 + koff] = s0;
            *(short8v*)&As[row * 136 + koff + 8] = s1;
        }
        // stage W: 128 n x 128 k (from WbT [n][k])
        {
            const int n = tid & 127, h2 = tid >> 7;
            #pragma unroll
            for (int i = 0; i < 8; i++) {
                const int koff = h2 * 64 + i * 8;
                *(short8v*)&Ws[n * 136 + koff] =
                    *(const short8v*)(WbT + (size_t)n * D_IN + kc0 + koff);
            }
        }
        __syncthreads();
        #pragma unroll
        for (int ks = 0; ks < 4; ks++) {
            const int ko = ks * 32 + quad * 8;
            const short8v af0 = *(const short8v*)&As[m16 * 136 + ko];
            const short8v af1 = *(const short8v*)&As[(16 + m16) * 136 + ko];
            const short8v bf0 = *(const short8v*)&Ws[(w * 32 + m16) * 136 + ko];
            const short8v bf1 = *(const short8v*)&Ws[(w * 32 + 16 + m16) * 136 + ko];
            acc[0][0] = __builtin_amdgcn_mfma_f32_16x16x32_bf16(af0, bf0, acc[0][0], 0, 0, 0);
            acc[0][1] = __builtin_amdgcn_mfma_f32_16x16x32_bf16(af0, bf1, acc[0][1], 0, 0, 0);
            acc[1][0] = __builtin_amdgcn_mfma_f32_16x16x32_bf16(af1, bf0, acc[1][0], 0, 0, 0);
            acc[1][1] = __builtin_amdgcn_mfma_f32_16x16x32_bf16(af1, bf1, acc[1][1], 0, 0, 0);
        }
    }

    // epilogue: WhT stores (feature-major), C/D layout col=lane&15, row=quad*4+reg
    #pragma unroll
    for (int mt = 0; mt < 2; mt++) {
        #pragma unroll
        for (int nt = 0; nt < 2; nt++) {
            const int n = w * 32 + nt * 16 + m16;
            short4v p;
            #pragma unroll
            for (int reg = 0; reg < 4; reg++) p[reg] = (short)f2bf(acc[mt][nt][reg]);
            *(short4v*)(WhT + (size_t)n * N_NODES + rowbase + mt * 16 + quad * 4) = p;
        }
    }

    // f1/f2 partials: f = Wh @ a-half
    float a1v[2], a2v[2];
    #pragma unroll
    for (int nt = 0; nt < 2; nt++) {
        a1v[nt] = a[w * 32 + nt * 16 + m16];
        a2v[nt] = a[D_OUT + w * 32 + nt * 16 + m16];
    }
    #pragma unroll
    for (int mt = 0; mt < 2; mt++)
        #pragma unroll
        for (int reg = 0; reg < 4; reg++) {
            const int row = mt * 16 + quad * 4 + reg;
            pf1[row][w * 16 + m16] = acc[mt][0][reg] * a1v[0] + acc[mt][1][reg] * a1v[1];
            pf2[row][w * 16 + m16] = acc[mt][0][reg] * a2v[0] + acc[mt][1][reg] * a2v[1];
        }
    __syncthreads();
    if (tid < 32) {
        float s = 0.f;
        #pragma unroll
        for (int j = 0; j < 64; j++) s += pf1[tid][j];
        f1[rowbase + tid] = s * LOG2E;
    } else if (tid < 64) {
        float s = 0.f;
        #pragma unroll
        for (int j = 0; j < 64; j++) s += pf2[tid - 32][j];
        f2[rowbase + tid - 32] = s * LOG2E;
    }
}

// ---------------- Kernel 2: fused mask+exp2 + partial PV via MFMA (direct adj reads) --------
// Block = 32 rows x 2048-col segment. Thread (r,g) owns cols [g*32, g*32+32) per 256-chunk:
// adj loads (a4), f2 reads, and Pt writes all use this SAME ownership.
__global__ __launch_bounds__(256, 4) void k2_attn(
        const int* __restrict__ adj, const u16* __restrict__ WhT,
        const float* __restrict__ f1g, const float* __restrict__ f2g,
        float* __restrict__ numw, float* __restrict__ denw)
{
    __shared__ short Pt[32 * 264];       // 16.9 KB, row stride 264 shorts
    __shared__ float f2s[2304];          // padded: 4-float pad per 32
    __shared__ float f1s[32];
    __shared__ float rs[32][9];
    __shared__ float ssum[32];

    const int tid = threadIdx.x;
    const int rb  = blockIdx.x >> 2;
    const int seg = blockIdx.x & 3;
    const int rowbase = rb * 32;
    const int colbase = seg * SEGCOLS;
    const int r = tid >> 3, g = tid & 7;
    const int lane = tid & 63, w = tid >> 6;
    const int quad = lane >> 4, m16 = lane & 15;

    if (tid < 32) f1s[tid] = f1g[rowbase + tid];
    #pragma unroll
    for (int i = 0; i < 2; i++) {
        const int idx = (tid + 256 * i) * 4;
        *(float4v*)&f2s[idx + ((idx >> 5) << 2)] = *(const float4v*)&f2g[colbase + idx];
    }

    const int4v* arow = (const int4v*)(adj + (size_t)(rowbase + r) * N_NODES + colbase);
    int4v a4[8];
    #pragma unroll
    for (int i = 0; i < 8; i++) a4[i] = arow[g * 8 + i];   // chunk 0, cols g*32+i*4..+4

    float4v acc[2][2];
    #pragma unroll
    for (int mt = 0; mt < 2; mt++)
        #pragma unroll
        for (int nt = 0; nt < 2; nt++) {
            acc[mt][nt][0] = 0.f; acc[mt][nt][1] = 0.f;
            acc[mt][nt][2] = 0.f; acc[mt][nt][3] = 0.f;
        }
    float ls0 = 0.f, ls1 = 0.f, ls2 = 0.f, ls3 = 0.f;

    __syncthreads();   // f1s/f2s ready

    for (int jc = 0; jc < NCHUNK; jc++) {
        // ---- weight phase: 32 consecutive cols per thread ----
        const float f1v = f1s[r];
        const float* f2p = &f2s[jc * 288 + g * 36];
        u32 packed[16];
        #pragma unroll
        for (int i = 0; i < 8; i++) {
            const float4v fv = *(const float4v*)&f2p[i * 4];
            const int4v av = a4[i];
            u32 wb[4];
            #pragma unroll
            for (int e = 0; e < 4; e++) {
                const u32 msk = (av[e] > 0) ? 0xffff0000u : 0u;
                float x = f1v + fv[e];
                x = fmaxf(x, SLOPEF * x);                            // leaky_relu (log2 domain)
                const float ex = __builtin_amdgcn_exp2f(x);
                const u32 wt = __float_as_uint(ex) & msk;            // masked + bf16-trunc
                wb[e] = wt;
                if (e == 0) ls0 += __uint_as_float(wt);
                else if (e == 1) ls1 += __uint_as_float(wt);
                else if (e == 2) ls2 += __uint_as_float(wt);
                else ls3 += __uint_as_float(wt);
            }
            packed[i * 2]     = __builtin_amdgcn_perm(wb[1], wb[0], 0x07060302);
            packed[i * 2 + 1] = __builtin_amdgcn_perm(wb[3], wb[2], 0x07060302);
        }
        {
            int* pdst = (int*)&Pt[r * 264 + g * 32];
            #pragma unroll
            for (int q = 0; q < 4; q++) {
                int4v st;
                st[0] = (int)packed[q * 4 + 0]; st[1] = (int)packed[q * 4 + 1];
                st[2] = (int)packed[q * 4 + 2]; st[3] = (int)packed[q * 4 + 3];
                *(int4v*)&pdst[q * 4] = st;
            }
        }
        // prefetch next adj chunk (same cols this thread masks next iteration);
        // stays in flight across the lds_barrier + MFMA phase
        if (jc + 1 < NCHUNK) {
            #pragma unroll
            for (int i = 0; i < 8; i++) a4[i] = arow[(jc + 1) * 64 + g * 8 + i];
        }
        lds_barrier();

        // ---- MFMA phase: acc += P[32 x 256] @ Wh[256 x 128] (this wave's 32 feature cols) ----
        {
            const u16* b0p = WhT + (size_t)(w * 32 + m16) * N_NODES + colbase + jc * 256 + quad * 8;
            const u16* b1p = b0p + 16 * N_NODES;
            const short* a0p = &Pt[m16 * 264 + quad * 8];
            const short* a1p = a0p + 16 * 264;
            #pragma unroll
            for (int ks = 0; ks < 8; ks++) {
                const int ko = ks * 32;
                const short8v af0 = *(const short8v*)(a0p + ko);
                const short8v af1 = *(const short8v*)(a1p + ko);
                const short8v bv0 = *(const short8v*)(b0p + ko);
                const short8v bv1 = *(const short8v*)(b1p + ko);
                acc[0][0] = __builtin_amdgcn_mfma_f32_16x16x32_bf16(af0, bv0, acc[0][0], 0, 0, 0);
                acc[0][1] = __builtin_amdgcn_mfma_f32_16x16x32_bf16(af0, bv1, acc[0][1], 0, 0, 0);
                acc[1][0] = __builtin_amdgcn_mfma_f32_16x16x32_bf16(af1, bv0, acc[1][0], 0, 0, 0);
                acc[1][1] = __builtin_amdgcn_mfma_f32_16x16x32_bf16(af1, bv1, acc[1][1], 0, 0, 0);
            }
        }
        lds_barrier();
    }

    // per-row partial denominator
    rs[r][g] = (ls0 + ls1) + (ls2 + ls3);
    __syncthreads();
    if (tid < 32) {
        float s = 0.f;
        #pragma unroll
        for (int j = 0; j < 8; j++) s += rs[tid][j];
        ssum[tid] = s;
        denw[(size_t)(rowbase + tid) * NSEG + seg] = s;
    }
    __syncthreads();

    // epilogue: write partial numerator. C/D layout col=lane&15, row=quad*4+reg
    #pragma unroll
    for (int mt = 0; mt < 2; mt++) {
        #pragma unroll
        for (int nt = 0; nt < 2; nt++) {
            const int cl = w * 32 + nt * 16 + m16;
            #pragma unroll
            for (int reg = 0; reg < 4; reg++) {
                const int rl = mt * 16 + quad * 4 + reg;
                numw[((size_t)(rowbase + rl) * NSEG + seg) * D_OUT + cl] = acc[mt][nt][reg];
            }
        }
    }
}

// ---------------- Kernel 3: reduce partials, divide, write output ----------------
__global__ __launch_bounds__(256) void k3_reduce(
        const float* __restrict__ numw, const float* __restrict__ denw,
        float* __restrict__ out)
{
    const int tid = threadIdx.x;
    const int row = blockIdx.x * 2 + (tid >> 7);
    const int c   = tid & 127;
    float s = 0.f, d = 0.f;
    #pragma unroll
    for (int sg = 0; sg < NSEG; sg++) {
        s += numw[((size_t)row * NSEG + sg) * D_OUT + c];
        d += denw[(size_t)row * NSEG + sg];
    }
    out[(size_t)row * D_OUT + c] = s / d;
}

extern "C" void kernel_launch(void* const* d_in, const int* in_sizes, int n_in,
                              void* d_out, int out_size, void* d_ws, size_t ws_size,
                              hipStream_t stream) {
    const float* h   = (const float*)d_in[0];
    const int*   adj = (const int*)d_in[1];
    const float* W   = (const float*)d_in[2];
    const float* a   = (const float*)d_in[3];

    char* ws = (char*)d_ws;
    u16*   hb   = (u16*)ws;                                    // 8 MB
    u16*   WbT  = (u16*)(ws + (size_t)8 * 1024 * 1024);        // 128 KB
    u16*   WhT  = (u16*)(ws + (size_t)9 * 1024 * 1024);        // 2 MB
    float* f1   = (float*)(ws + (size_t)11 * 1024 * 1024);     // 32 KB
    float* f2   = f1 + N_NODES;                                // 32 KB
    float* numw = (float*)(ws + (size_t)12 * 1024 * 1024);     // 16 MB
    float* denw = (float*)(ws + (size_t)28 * 1024 * 1024);     // 128 KB

    kc_convert<<<2080, 256, 0, stream>>>(h, W, hb, WbT);
    k1m_proj<<<N_NODES / 32, 256, 0, stream>>>(hb, WbT, a, WhT, f1, f2);
    k2_attn<<<(N_NODES / 32) * NSEG, 256, 0, stream>>>(adj, WhT, f1, f2, numw, denw);
    k3_reduce<<<N_NODES / 2, 256, 0, stream>>>(numw, denw, (float*)d_out);
}

// Round 9
// 415.061 us; speedup vs baseline: 1.1641x; 1.0121x over previous
//
#include <hip/hip_runtime.h>

typedef unsigned short u16;
typedef unsigned int u32;
typedef __attribute__((ext_vector_type(8))) short short8v;
typedef __attribute__((ext_vector_type(4))) short short4v;
typedef __attribute__((ext_vector_type(4))) float float4v;
typedef __attribute__((ext_vector_type(4))) int   int4v;

#define N_NODES 8192
#define D_IN    512
#define D_OUT   128
#define SLOPEF  0.2f
#define LOG2E   1.4426950408889634f
#define NSEG    4
#define SEGCOLS 2048   // N_NODES / NSEG
#define NCHUNK  8      // SEGCOLS / 256

static __device__ __forceinline__ u16 f2bf(float f) {
    union { float f; unsigned int i; } v; v.f = f;
    unsigned int r = v.i + 0x7fff + ((v.i >> 16) & 1);
    return (u16)(r >> 16);
}
static __device__ __forceinline__ void lds_barrier() {
    asm volatile("s_waitcnt lgkmcnt(0)" ::: "memory");
    __builtin_amdgcn_s_barrier();
    asm volatile("" ::: "memory");
}

// ---------------- Kernel C: fp32 -> bf16 convert (h -> hb row-major, W -> WbT [n][k]) --------
__global__ __launch_bounds__(256) void kc_convert(
        const float* __restrict__ h, const float* __restrict__ W,
        u16* __restrict__ hb, u16* __restrict__ WbT)
{
    if (blockIdx.x < 2048) {
        const size_t t = (size_t)blockIdx.x * 256 + threadIdx.x;   // 524288 threads x 8 elems
        const float4v* src = (const float4v*)h + t * 2;
        const float4v v0 = src[0], v1 = src[1];
        short8v o;
        o[0] = (short)f2bf(v0[0]); o[1] = (short)f2bf(v0[1]);
        o[2] = (short)f2bf(v0[2]); o[3] = (short)f2bf(v0[3]);
        o[4] = (short)f2bf(v1[0]); o[5] = (short)f2bf(v1[1]);
        o[6] = (short)f2bf(v1[2]); o[7] = (short)f2bf(v1[3]);
        *(short8v*)(hb + t * 8) = o;
    } else {
        const int t2 = (blockIdx.x - 2048) * 256 + threadIdx.x;    // 0..8191
        const int k = t2 >> 4;            // 512 k values
        const int n0 = (t2 & 15) * 8;     // 8 consecutive n
        const float4v* src = (const float4v*)(W + (size_t)k * D_OUT + n0);
        const float4v v0 = src[0], v1 = src[1];
        #pragma unroll
        for (int e = 0; e < 4; e++) WbT[(size_t)(n0 + e) * D_IN + k] = f2bf(v0[e]);
        #pragma unroll
        for (int e = 0; e < 4; e++) WbT[(size_t)(n0 + 4 + e) * D_IN + k] = f2bf(v1[e]);
    }
}

// ---------------- Kernel 1M: Wh = h@W via MFMA; WhT bf16 [128][8192]; f1,f2 (x log2e) --------
__global__ __launch_bounds__(256) void k1m_proj(
        const u16* __restrict__ hb, const u16* __restrict__ WbT,
        const float* __restrict__ a, u16* __restrict__ WhT,
        float* __restrict__ f1, float* __restrict__ f2)
{
    __shared__ short As[32 * 136];     // 8.5 KB, stride 136 shorts
    __shared__ short Ws[128 * 136];    // 34 KB
    __shared__ float pf1[32][65];      // 8.3 KB
    __shared__ float pf2[32][65];      // 8.3 KB

    const int tid = threadIdx.x;
    const int rowbase = blockIdx.x * 32;
    const int lane = tid & 63, w = tid >> 6;
    const int quad = lane >> 4, m16 = lane & 15;

    float4v acc[2][2];
    #pragma unroll
    for (int mt = 0; mt < 2; mt++)
        #pragma unroll
        for (int nt = 0; nt < 2; nt++) {
            acc[mt][nt][0] = 0.f; acc[mt][nt][1] = 0.f;
            acc[mt][nt][2] = 0.f; acc[mt][nt][3] = 0.f;
        }

    for (int c = 0; c < 4; c++) {
        const int kc0 = c * 128;
        if (c) __syncthreads();   // prev chunk's LDS reads done
        {
            const int row = tid >> 3, koff = (tid & 7) * 16;
            const short8v* src = (const short8v*)(hb + (size_t)(rowbase + row) * D_IN + kc0 + koff);
            const short8v s0 = src[0], s1 = src[1];
            *(short8v*)&As[row * 136 + koff] = s0;
            *(short8v*)&As[row * 136 + koff + 8] = s1;
        }
        {
            const int n = tid & 127, h2 = tid >> 7;
            #pragma unroll
            for (int i = 0; i < 8; i++) {
                const int koff = h2 * 64 + i * 8;
                *(short8v*)&Ws[n * 136 + koff] =
                    *(const short8v*)(WbT + (size_t)n * D_IN + kc0 + koff);
            }
        }
        __syncthreads();
        #pragma unroll
        for (int ks = 0; ks < 4; ks++) {
            const int ko = ks * 32 + quad * 8;
            const short8v af0 = *(const short8v*)&As[m16 * 136 + ko];
            const short8v af1 = *(const short8v*)&As[(16 + m16) * 136 + ko];
            const short8v bf0 = *(const short8v*)&Ws[(w * 32 + m16) * 136 + ko];
            const short8v bf1 = *(const short8v*)&Ws[(w * 32 + 16 + m16) * 136 + ko];
            acc[0][0] = __builtin_amdgcn_mfma_f32_16x16x32_bf16(af0, bf0, acc[0][0], 0, 0, 0);
            acc[0][1] = __builtin_amdgcn_mfma_f32_16x16x32_bf16(af0, bf1, acc[0][1], 0, 0, 0);
            acc[1][0] = __builtin_amdgcn_mfma_f32_16x16x32_bf16(af1, bf0, acc[1][0], 0, 0, 0);
            acc[1][1] = __builtin_amdgcn_mfma_f32_16x16x32_bf16(af1, bf1, acc[1][1], 0, 0, 0);
        }
    }

    // epilogue: WhT stores (feature-major), C/D layout col=lane&15, row=quad*4+reg
    #pragma unroll
    for (int mt = 0; mt < 2; mt++) {
        #pragma unroll
        for (int nt = 0; nt < 2; nt++) {
            const int n = w * 32 + nt * 16 + m16;
            short4v p;
            #pragma unroll
            for (int reg = 0; reg < 4; reg++) p[reg] = (short)f2bf(acc[mt][nt][reg]);
            *(short4v*)(WhT + (size_t)n * N_NODES + rowbase + mt * 16 + quad * 4) = p;
        }
    }

    float a1v[2], a2v[2];
    #pragma unroll
    for (int nt = 0; nt < 2; nt++) {
        a1v[nt] = a[w * 32 + nt * 16 + m16];
        a2v[nt] = a[D_OUT + w * 32 + nt * 16 + m16];
    }
    #pragma unroll
    for (int mt = 0; mt < 2; mt++)
        #pragma unroll
        for (int reg = 0; reg < 4; reg++) {
            const int row = mt * 16 + quad * 4 + reg;
            pf1[row][w * 16 + m16] = acc[mt][0][reg] * a1v[0] + acc[mt][1][reg] * a1v[1];
            pf2[row][w * 16 + m16] = acc[mt][0][reg] * a2v[0] + acc[mt][1][reg] * a2v[1];
        }
    __syncthreads();
    if (tid < 32) {
        float s = 0.f;
        #pragma unroll
        for (int j = 0; j < 64; j++) s += pf1[tid][j];
        f1[rowbase + tid] = s * LOG2E;
    } else if (tid < 64) {
        float s = 0.f;
        #pragma unroll
        for (int j = 0; j < 64; j++) s += pf2[tid - 32][j];
        f2[rowbase + tid - 32] = s * LOG2E;
    }
}

// ---------------- Kernel 2: fused mask+exp2 + partial PV via MFMA, dbuf Pt, 1 barrier/chunk --
// Block = 32 rows x 2048-col segment. Thread (r,g) owns cols [g*32, g*32+32) per 256-chunk.
// Region between barriers: mfma(jc, buf jc&1) + weight(jc+1 -> buf (jc+1)&1) + adj prefetch.
__global__ __launch_bounds__(256, 3) void k2_attn(
        const int* __restrict__ adj, const u16* __restrict__ WhT,
        const float* __restrict__ f1g, const float* __restrict__ f2g,
        float* __restrict__ numw, float* __restrict__ denw)
{
    __shared__ short Pt[2][32 * 264];    // 33.8 KB double-buffered P tile
    __shared__ float f2s[2304];          // padded: 4-float pad per 32
    __shared__ float f1s[32];
    __shared__ float rs[32][9];
    __shared__ float ssum[32];

    const int tid = threadIdx.x;
    const int rb  = blockIdx.x >> 2;
    const int seg = blockIdx.x & 3;
    const int rowbase = rb * 32;
    const int colbase = seg * SEGCOLS;
    const int r = tid >> 3, g = tid & 7;
    const int lane = tid & 63, w = tid >> 6;
    const int quad = lane >> 4, m16 = lane & 15;

    if (tid < 32) f1s[tid] = f1g[rowbase + tid];
    #pragma unroll
    for (int i = 0; i < 2; i++) {
        const int idx = (tid + 256 * i) * 4;
        *(float4v*)&f2s[idx + ((idx >> 5) << 2)] = *(const float4v*)&f2g[colbase + idx];
    }

    const int4v* arow = (const int4v*)(adj + (size_t)(rowbase + r) * N_NODES + colbase);
    int4v a4[8];
    #pragma unroll
    for (int i = 0; i < 8; i++) a4[i] = arow[g * 8 + i];   // chunk 0, cols g*32..+31

    float4v acc[2][2];
    #pragma unroll
    for (int mt = 0; mt < 2; mt++)
        #pragma unroll
        for (int nt = 0; nt < 2; nt++) {
            acc[mt][nt][0] = 0.f; acc[mt][nt][1] = 0.f;
            acc[mt][nt][2] = 0.f; acc[mt][nt][3] = 0.f;
        }
    float ls0 = 0.f, ls1 = 0.f, ls2 = 0.f, ls3 = 0.f;

    __syncthreads();   // f1s/f2s ready

    const float f1v = f1s[r];

    auto weight_phase = [&](int jc, short* ptb) {
        const float* f2p = &f2s[jc * 288 + g * 36];
        u32 packed[16];
        #pragma unroll
        for (int i = 0; i < 8; i++) {
            const float4v fv = *(const float4v*)&f2p[i * 4];
            const int4v av = a4[i];
            u32 wb[4];
            #pragma unroll
            for (int e = 0; e < 4; e++) {
                const u32 msk = (av[e] > 0) ? 0xffff0000u : 0u;
                float x = f1v + fv[e];
                x = fmaxf(x, SLOPEF * x);                            // leaky_relu (log2 domain)
                const float ex = __builtin_amdgcn_exp2f(x);
                const u32 wt = __float_as_uint(ex) & msk;            // masked + bf16-trunc
                wb[e] = wt;
                if (e == 0) ls0 += __uint_as_float(wt);
                else if (e == 1) ls1 += __uint_as_float(wt);
                else if (e == 2) ls2 += __uint_as_float(wt);
                else ls3 += __uint_as_float(wt);
            }
            packed[i * 2]     = __builtin_amdgcn_perm(wb[1], wb[0], 0x07060302);
            packed[i * 2 + 1] = __builtin_amdgcn_perm(wb[3], wb[2], 0x07060302);
        }
        int* pdst = (int*)(ptb + r * 264 + g * 32);
        #pragma unroll
        for (int q = 0; q < 4; q++) {
            int4v st;
            st[0] = (int)packed[q * 4 + 0]; st[1] = (int)packed[q * 4 + 1];
            st[2] = (int)packed[q * 4 + 2]; st[3] = (int)packed[q * 4 + 3];
            *(int4v*)&pdst[q * 4] = st;
        }
    };

    // prologue: weight(0) into buf0, then prefetch chunk 1
    weight_phase(0, Pt[0]);
    #pragma unroll
    for (int i = 0; i < 8; i++) a4[i] = arow[64 + g * 8 + i];

    #pragma unroll 2
    for (int jc = 0; jc < NCHUNK; jc++) {
        lds_barrier();   // Pt[jc&1] complete across block; Pt[(jc+1)&1] free for writing

        // ---- MFMA phase: acc += P[32 x 256] @ Wh[256 x 128] (this wave's 32 feature cols) ----
        {
            const u16* b0p = WhT + (size_t)(w * 32 + m16) * N_NODES + colbase + jc * 256 + quad * 8;
            const u16* b1p = b0p + 16 * N_NODES;
            const short* a0p = &Pt[jc & 1][m16 * 264 + quad * 8];
            const short* a1p = a0p + 16 * 264;
            #pragma unroll
            for (int ks = 0; ks < 8; ks++) {
                const int ko = ks * 32;
                const short8v af0 = *(const short8v*)(a0p + ko);
                const short8v af1 = *(const short8v*)(a1p + ko);
                const short8v bv0 = *(const short8v*)(b0p + ko);
                const short8v bv1 = *(const short8v*)(b1p + ko);
                acc[0][0] = __builtin_amdgcn_mfma_f32_16x16x32_bf16(af0, bv0, acc[0][0], 0, 0, 0);
                acc[0][1] = __builtin_amdgcn_mfma_f32_16x16x32_bf16(af0, bv1, acc[0][1], 0, 0, 0);
                acc[1][0] = __builtin_amdgcn_mfma_f32_16x16x32_bf16(af1, bv0, acc[1][0], 0, 0, 0);
                acc[1][1] = __builtin_amdgcn_mfma_f32_16x16x32_bf16(af1, bv1, acc[1][1], 0, 0, 0);
            }
        }
        // ---- next chunk's weight phase overlaps this chunk's B-load/MFMA latency ----
        if (jc + 1 < NCHUNK) {
            weight_phase(jc + 1, Pt[(jc + 1) & 1]);
            if (jc + 2 < NCHUNK) {
                #pragma unroll
                for (int i = 0; i < 8; i++) a4[i] = arow[(jc + 2) * 64 + g * 8 + i];
            }
        }
    }

    // per-row partial denominator
    rs[r][g] = (ls0 + ls1) + (ls2 + ls3);
    __syncthreads();
    if (tid < 32) {
        float s = 0.f;
        #pragma unroll
        for (int j = 0; j < 8; j++) s += rs[tid][j];
        ssum[tid] = s;
        denw[(size_t)(rowbase + tid) * NSEG + seg] = s;
    }
    __syncthreads();

    // epilogue: write partial numerator. C/D layout col=lane&15, row=quad*4+reg
    #pragma unroll
    for (int mt = 0; mt < 2; mt++) {
        #pragma unroll
        for (int nt = 0; nt < 2; nt++) {
            const int cl = w * 32 + nt * 16 + m16;
            #pragma unroll
            for (int reg = 0; reg < 4; reg++) {
                const int rl = mt * 16 + quad * 4 + reg;
                numw[((size_t)(rowbase + rl) * NSEG + seg) * D_OUT + cl] = acc[mt][nt][reg];
            }
        }
    }
}

// ---------------- Kernel 3: reduce partials, divide, write output ----------------
__global__ __launch_bounds__(256) void k3_reduce(
        const float* __restrict__ numw, const float* __restrict__ denw,
        float* __restrict__ out)
{
    const int tid = threadIdx.x;
    const int row = blockIdx.x * 2 + (tid >> 7);
    const int c   = tid & 127;
    float s = 0.f, d = 0.f;
    #pragma unroll
    for (int sg = 0; sg < NSEG; sg++) {
        s += numw[((size_t)row * NSEG + sg) * D_OUT + c];
        d += denw[(size_t)row * NSEG + sg];
    }
    out[(size_t)row * D_OUT + c] = s / d;
}

extern "C" void kernel_launch(void* const* d_in, const int* in_sizes, int n_in,
                              void* d_out, int out_size, void* d_ws, size_t ws_size,
                              hipStream_t stream) {
    const float* h   = (const float*)d_in[0];
    const int*   adj = (const int*)d_in[1];
    const float* W   = (const float*)d_in[2];
    const float* a   = (const float*)d_in[3];

    char* ws = (char*)d_ws;
    u16*   hb   = (u16*)ws;                                    // 8 MB
    u16*   WbT  = (u16*)(ws + (size_t)8 * 1024 * 1024);        // 128 KB
    u16*   WhT  = (u16*)(ws + (size_t)9 * 1024 * 1024);        // 2 MB
    float* f1   = (float*)(ws + (size_t)11 * 1024 * 1024);     // 32 KB
    float* f2   = f1 + N_NODES;                                // 32 KB
    float* numw = (float*)(ws + (size_t)12 * 1024 * 1024);     // 16 MB
    float* denw = (float*)(ws + (size_t)28 * 1024 * 1024);     // 128 KB

    kc_convert<<<2080, 256, 0, stream>>>(h, W, hb, WbT);
    k1m_proj<<<N_NODES / 32, 256, 0, stream>>>(hb, WbT, a, WhT, f1, f2);
    k2_attn<<<(N_NODES / 32) * NSEG, 256, 0, stream>>>(adj, WhT, f1, f2, numw, denw);
    k3_reduce<<<N_NODES / 2, 256, 0, stream>>>(numw, denw, (float*)d_out);
}

// Round 10
// 411.389 us; speedup vs baseline: 1.1745x; 1.0089x over previous
//
#include <hip/hip_runtime.h>

typedef unsigned short u16;
typedef unsigned int u32;
typedef __attribute__((ext_vector_type(8))) short short8v;
typedef __attribute__((ext_vector_type(4))) short short4v;
typedef __attribute__((ext_vector_type(4))) float float4v;
typedef __attribute__((ext_vector_type(4))) int   int4v;

#define N_NODES 8192
#define D_IN    512
#define D_OUT   128
#define SLOPEF  0.2f
#define LOG2E   1.4426950408889634f
#define NSEG    4
#define SEGCOLS 2048   // N_NODES / NSEG
#define NCHUNK  16     // SEGCOLS / 128 (128-col chunks)

static __device__ __forceinline__ u16 f2bf(float f) {
    union { float f; unsigned int i; } v; v.f = f;
    unsigned int r = v.i + 0x7fff + ((v.i >> 16) & 1);
    return (u16)(r >> 16);
}
static __device__ __forceinline__ void lds_barrier() {
    asm volatile("s_waitcnt lgkmcnt(0)" ::: "memory");
    __builtin_amdgcn_s_barrier();
    asm volatile("" ::: "memory");
}

// ---------------- Kernel C: fp32 -> bf16 convert (h -> hb row-major, W -> WbT [n][k]) --------
__global__ __launch_bounds__(256) void kc_convert(
        const float* __restrict__ h, const float* __restrict__ W,
        u16* __restrict__ hb, u16* __restrict__ WbT)
{
    if (blockIdx.x < 2048) {
        const size_t t = (size_t)blockIdx.x * 256 + threadIdx.x;
        const float4v* src = (const float4v*)h + t * 2;
        const float4v v0 = src[0], v1 = src[1];
        short8v o;
        o[0] = (short)f2bf(v0[0]); o[1] = (short)f2bf(v0[1]);
        o[2] = (short)f2bf(v0[2]); o[3] = (short)f2bf(v0[3]);
        o[4] = (short)f2bf(v1[0]); o[5] = (short)f2bf(v1[1]);
        o[6] = (short)f2bf(v1[2]); o[7] = (short)f2bf(v1[3]);
        *(short8v*)(hb + t * 8) = o;
    } else {
        const int t2 = (blockIdx.x - 2048) * 256 + threadIdx.x;
        const int k = t2 >> 4;
        const int n0 = (t2 & 15) * 8;
        const float4v* src = (const float4v*)(W + (size_t)k * D_OUT + n0);
        const float4v v0 = src[0], v1 = src[1];
        #pragma unroll
        for (int e = 0; e < 4; e++) WbT[(size_t)(n0 + e) * D_IN + k] = f2bf(v0[e]);
        #pragma unroll
        for (int e = 0; e < 4; e++) WbT[(size_t)(n0 + 4 + e) * D_IN + k] = f2bf(v1[e]);
    }
}

// ---------------- Kernel 1M: Wh = h@W via MFMA; WhT bf16 [128][8192]; f1,f2 (x log2e) --------
__global__ __launch_bounds__(256) void k1m_proj(
        const u16* __restrict__ hb, const u16* __restrict__ WbT,
        const float* __restrict__ a, u16* __restrict__ WhT,
        float* __restrict__ f1, float* __restrict__ f2)
{
    __shared__ short As[32 * 136];
    __shared__ short Ws[128 * 136];
    __shared__ float pf1[32][65];
    __shared__ float pf2[32][65];

    const int tid = threadIdx.x;
    const int rowbase = blockIdx.x * 32;
    const int lane = tid & 63, w = tid >> 6;
    const int quad = lane >> 4, m16 = lane & 15;

    float4v acc[2][2];
    #pragma unroll
    for (int mt = 0; mt < 2; mt++)
        #pragma unroll
        for (int nt = 0; nt < 2; nt++) {
            acc[mt][nt][0] = 0.f; acc[mt][nt][1] = 0.f;
            acc[mt][nt][2] = 0.f; acc[mt][nt][3] = 0.f;
        }

    for (int c = 0; c < 4; c++) {
        const int kc0 = c * 128;
        if (c) __syncthreads();
        {
            const int row = tid >> 3, koff = (tid & 7) * 16;
            const short8v* src = (const short8v*)(hb + (size_t)(rowbase + row) * D_IN + kc0 + koff);
            const short8v s0 = src[0], s1 = src[1];
            *(short8v*)&As[row * 136 + koff] = s0;
            *(short8v*)&As[row * 136 + koff + 8] = s1;
        }
        {
            const int n = tid & 127, h2 = tid >> 7;
            #pragma unroll
            for (int i = 0; i < 8; i++) {
                const int koff = h2 * 64 + i * 8;
                *(short8v*)&Ws[n * 136 + koff] =
                    *(const short8v*)(WbT + (size_t)n * D_IN + kc0 + koff);
            }
        }
        __syncthreads();
        #pragma unroll
        for (int ks = 0; ks < 4; ks++) {
            const int ko = ks * 32 + quad * 8;
            const short8v af0 = *(const short8v*)&As[m16 * 136 + ko];
            const short8v af1 = *(const short8v*)&As[(16 + m16) * 136 + ko];
            const short8v bf0 = *(const short8v*)&Ws[(w * 32 + m16) * 136 + ko];
            const short8v bf1 = *(const short8v*)&Ws[(w * 32 + 16 + m16) * 136 + ko];
            acc[0][0] = __builtin_amdgcn_mfma_f32_16x16x32_bf16(af0, bf0, acc[0][0], 0, 0, 0);
            acc[0][1] = __builtin_amdgcn_mfma_f32_16x16x32_bf16(af0, bf1, acc[0][1], 0, 0, 0);
            acc[1][0] = __builtin_amdgcn_mfma_f32_16x16x32_bf16(af1, bf0, acc[1][0], 0, 0, 0);
            acc[1][1] = __builtin_amdgcn_mfma_f32_16x16x32_bf16(af1, bf1, acc[1][1], 0, 0, 0);
        }
    }

    #pragma unroll
    for (int mt = 0; mt < 2; mt++) {
        #pragma unroll
        for (int nt = 0; nt < 2; nt++) {
            const int n = w * 32 + nt * 16 + m16;
            short4v p;
            #pragma unroll
            for (int reg = 0; reg < 4; reg++) p[reg] = (short)f2bf(acc[mt][nt][reg]);
            *(short4v*)(WhT + (size_t)n * N_NODES + rowbase + mt * 16 + quad * 4) = p;
        }
    }

    float a1v[2], a2v[2];
    #pragma unroll
    for (int nt = 0; nt < 2; nt++) {
        a1v[nt] = a[w * 32 + nt * 16 + m16];
        a2v[nt] = a[D_OUT + w * 32 + nt * 16 + m16];
    }
    #pragma unroll
    for (int mt = 0; mt < 2; mt++)
        #pragma unroll
        for (int reg = 0; reg < 4; reg++) {
            const int row = mt * 16 + quad * 4 + reg;
            pf1[row][w * 16 + m16] = acc[mt][0][reg] * a1v[0] + acc[mt][1][reg] * a1v[1];
            pf2[row][w * 16 + m16] = acc[mt][0][reg] * a2v[0] + acc[mt][1][reg] * a2v[1];
        }
    __syncthreads();
    if (tid < 32) {
        float s = 0.f;
        #pragma unroll
        for (int j = 0; j < 64; j++) s += pf1[tid][j];
        f1[rowbase + tid] = s * LOG2E;
    } else if (tid < 64) {
        float s = 0.f;
        #pragma unroll
        for (int j = 0; j < 64; j++) s += pf2[tid - 32][j];
        f2[rowbase + tid - 32] = s * LOG2E;
    }
}

// ---------------- Kernel 2: fused mask+exp2 + partial PV via MFMA ----------------
// 128-col chunks, double-buffered Pt, ONE barrier per chunk, 5 blocks/CU (20 waves).
// Thread (r,g) owns cols [g*16, g*16+16) of each chunk for adj/f2/Pt.
__global__ __launch_bounds__(256, 5) void k2_attn(
        const int* __restrict__ adj, const u16* __restrict__ WhT,
        const float* __restrict__ f1g, const float* __restrict__ f2g,
        float* __restrict__ numw, float* __restrict__ denw)
{
    __shared__ short Pt[2][32 * 136];    // 17 KB double-buffered P tile (stride 136 shorts)
    __shared__ float f2s[2304];          // 2048 + 4-float pad per 32 (bank-spread)
    __shared__ float f1s[32];
    __shared__ float rs[32][9];
    __shared__ float ssum[32];

    const int tid = threadIdx.x;
    const int rb  = blockIdx.x >> 2;
    const int seg = blockIdx.x & 3;
    const int rowbase = rb * 32;
    const int colbase = seg * SEGCOLS;
    const int r = tid >> 3, g = tid & 7;
    const int lane = tid & 63, w = tid >> 6;
    const int quad = lane >> 4, m16 = lane & 15;

    if (tid < 32) f1s[tid] = f1g[rowbase + tid];
    #pragma unroll
    for (int i = 0; i < 2; i++) {
        const int idx = (tid + 256 * i) * 4;
        *(float4v*)&f2s[idx + ((idx >> 5) << 2)] = *(const float4v*)&f2g[colbase + idx];
    }

    const int4v* arow = (const int4v*)(adj + (size_t)(rowbase + r) * N_NODES + colbase);
    int4v a4[4];
    #pragma unroll
    for (int i = 0; i < 4; i++) a4[i] = arow[g * 4 + i];   // chunk 0: cols g*16..+15

    float4v acc[2][2];
    #pragma unroll
    for (int mt = 0; mt < 2; mt++)
        #pragma unroll
        for (int nt = 0; nt < 2; nt++) {
            acc[mt][nt][0] = 0.f; acc[mt][nt][1] = 0.f;
            acc[mt][nt][2] = 0.f; acc[mt][nt][3] = 0.f;
        }
    float ls0 = 0.f, ls1 = 0.f, ls2 = 0.f, ls3 = 0.f;

    __syncthreads();   // f1s/f2s ready

    const float f1v = f1s[r];
    // padded f2 base offset for this thread's 16 cols within a chunk
    const int f2off = (g >> 1) * 36 + (g & 1) * 16;

    auto weight_phase = [&](int jc, short* ptb) {
        const float* f2p = &f2s[jc * 144 + f2off];
        u32 packed[8];
        #pragma unroll
        for (int i = 0; i < 4; i++) {
            const float4v fv = *(const float4v*)&f2p[i * 4];
            const int4v av = a4[i];
            u32 wb[4];
            #pragma unroll
            for (int e = 0; e < 4; e++) {
                const u32 msk = (av[e] > 0) ? 0xffff0000u : 0u;
                float x = f1v + fv[e];
                x = fmaxf(x, SLOPEF * x);                            // leaky_relu (log2 domain)
                const float ex = __builtin_amdgcn_exp2f(x);
                const u32 wt = __float_as_uint(ex) & msk;            // masked + bf16-trunc
                wb[e] = wt;
                if (e == 0) ls0 += __uint_as_float(wt);
                else if (e == 1) ls1 += __uint_as_float(wt);
                else if (e == 2) ls2 += __uint_as_float(wt);
                else ls3 += __uint_as_float(wt);
            }
            packed[i * 2]     = __builtin_amdgcn_perm(wb[1], wb[0], 0x07060302);
            packed[i * 2 + 1] = __builtin_amdgcn_perm(wb[3], wb[2], 0x07060302);
        }
        int* pdst = (int*)(ptb + r * 136 + g * 16);
        {
            int4v st0, st1;
            st0[0] = (int)packed[0]; st0[1] = (int)packed[1];
            st0[2] = (int)packed[2]; st0[3] = (int)packed[3];
            st1[0] = (int)packed[4]; st1[1] = (int)packed[5];
            st1[2] = (int)packed[6]; st1[3] = (int)packed[7];
            *(int4v*)&pdst[0] = st0;
            *(int4v*)&pdst[4] = st1;
        }
    };

    // prologue: weight(0) into buf0, then prefetch chunk 1
    weight_phase(0, Pt[0]);
    #pragma unroll
    for (int i = 0; i < 4; i++) a4[i] = arow[32 + g * 4 + i];

    #pragma unroll 2
    for (int jc = 0; jc < NCHUNK; jc++) {
        lds_barrier();   // Pt[jc&1] complete; Pt[(jc+1)&1] free

        // ---- MFMA: acc += P[32 x 128] @ Wh[128 x 128] (this wave's 32 feature cols) ----
        {
            const u16* b0p = WhT + (size_t)(w * 32 + m16) * N_NODES + colbase + jc * 128 + quad * 8;
            const u16* b1p = b0p + 16 * N_NODES;
            const short* a0p = &Pt[jc & 1][m16 * 136 + quad * 8];
            const short* a1p = a0p + 16 * 136;
            #pragma unroll
            for (int ks = 0; ks < 4; ks++) {
                const int ko = ks * 32;
                const short8v af0 = *(const short8v*)(a0p + ko);
                const short8v af1 = *(const short8v*)(a1p + ko);
                const short8v bv0 = *(const short8v*)(b0p + ko);
                const short8v bv1 = *(const short8v*)(b1p + ko);
                acc[0][0] = __builtin_amdgcn_mfma_f32_16x16x32_bf16(af0, bv0, acc[0][0], 0, 0, 0);
                acc[0][1] = __builtin_amdgcn_mfma_f32_16x16x32_bf16(af0, bv1, acc[0][1], 0, 0, 0);
                acc[1][0] = __builtin_amdgcn_mfma_f32_16x16x32_bf16(af1, bv0, acc[1][0], 0, 0, 0);
                acc[1][1] = __builtin_amdgcn_mfma_f32_16x16x32_bf16(af1, bv1, acc[1][1], 0, 0, 0);
            }
        }
        // ---- next chunk's weight phase overlaps this chunk's B-load/MFMA latency ----
        if (jc + 1 < NCHUNK) {
            weight_phase(jc + 1, Pt[(jc + 1) & 1]);
            if (jc + 2 < NCHUNK) {
                #pragma unroll
                for (int i = 0; i < 4; i++) a4[i] = arow[(jc + 2) * 32 + g * 4 + i];
            }
        }
    }

    // per-row partial denominator
    rs[r][g] = (ls0 + ls1) + (ls2 + ls3);
    __syncthreads();
    if (tid < 32) {
        float s = 0.f;
        #pragma unroll
        for (int j = 0; j < 8; j++) s += rs[tid][j];
        ssum[tid] = s;
        denw[(size_t)(rowbase + tid) * NSEG + seg] = s;
    }
    __syncthreads();

    // epilogue: write partial numerator. C/D layout col=lane&15, row=quad*4+reg
    #pragma unroll
    for (int mt = 0; mt < 2; mt++) {
        #pragma unroll
        for (int nt = 0; nt < 2; nt++) {
            const int cl = w * 32 + nt * 16 + m16;
            #pragma unroll
            for (int reg = 0; reg < 4; reg++) {
                const int rl = mt * 16 + quad * 4 + reg;
                numw[((size_t)(rowbase + rl) * NSEG + seg) * D_OUT + cl] = acc[mt][nt][reg];
            }
        }
    }
}

// ---------------- Kernel 3: reduce partials, divide, write output ----------------
__global__ __launch_bounds__(256) void k3_reduce(
        const float* __restrict__ numw, const float* __restrict__ denw,
        float* __restrict__ out)
{
    const int tid = threadIdx.x;
    const int row = blockIdx.x * 2 + (tid >> 7);
    const int c   = tid & 127;
    float s = 0.f, d = 0.f;
    #pragma unroll
    for (int sg = 0; sg < NSEG; sg++) {
        s += numw[((size_t)row * NSEG + sg) * D_OUT + c];
        d += denw[(size_t)row * NSEG + sg];
    }
    out[(size_t)row * D_OUT + c] = s / d;
}

extern "C" void kernel_launch(void* const* d_in, const int* in_sizes, int n_in,
                              void* d_out, int out_size, void* d_ws, size_t ws_size,
                              hipStream_t stream) {
    const float* h   = (const float*)d_in[0];
    const int*   adj = (const int*)d_in[1];
    const float* W   = (const float*)d_in[2];
    const float* a   = (const float*)d_in[3];

    char* ws = (char*)d_ws;
    u16*   hb   = (u16*)ws;                                    // 8 MB
    u16*   WbT  = (u16*)(ws + (size_t)8 * 1024 * 1024);        // 128 KB
    u16*   WhT  = (u16*)(ws + (size_t)9 * 1024 * 1024);        // 2 MB
    float* f1   = (float*)(ws + (size_t)11 * 1024 * 1024);     // 32 KB
    float* f2   = f1 + N_NODES;                                // 32 KB
    float* numw = (float*)(ws + (size_t)12 * 1024 * 1024);     // 16 MB
    float* denw = (float*)(ws + (size_t)28 * 1024 * 1024);     // 128 KB

    kc_convert<<<2080, 256, 0, stream>>>(h, W, hb, WbT);
    k1m_proj<<<N_NODES / 32, 256, 0, stream>>>(hb, WbT, a, WhT, f1, f2);
    k2_attn<<<(N_NODES / 32) * NSEG, 256, 0, stream>>>(adj, WhT, f1, f2, numw, denw);
    k3_reduce<<<N_NODES / 2, 256, 0, stream>>>(numw, denw, (float*)d_out);
}

// Round 11
// 398.652 us; speedup vs baseline: 1.2120x; 1.0320x over previous
//
#include <hip/hip_runtime.h>

typedef unsigned short u16;
typedef unsigned int u32;
typedef __attribute__((ext_vector_type(8))) short short8v;
typedef __attribute__((ext_vector_type(4))) short short4v;
typedef __attribute__((ext_vector_type(4))) float float4v;
typedef __attribute__((ext_vector_type(4))) int   int4v;

#define N_NODES 8192
#define D_IN    512
#define D_OUT   128
#define SLOPEF  0.2f
#define LOG2E   1.4426950408889634f
#define NSEG    4
#define SEGCOLS 2048   // N_NODES / NSEG
#define NCHUNK  16     // SEGCOLS / 128 (128-col chunks)
#define ROWS    64     // rows per block

static __device__ __forceinline__ u16 f2bf(float f) {
    union { float f; unsigned int i; } v; v.f = f;
    unsigned int r = v.i + 0x7fff + ((v.i >> 16) & 1);
    return (u16)(r >> 16);
}
static __device__ __forceinline__ void lds_barrier() {
    asm volatile("s_waitcnt lgkmcnt(0)" ::: "memory");
    __builtin_amdgcn_s_barrier();
    asm volatile("" ::: "memory");
}

// ---------------- Kernel C: fp32 -> bf16 convert (h -> hb row-major, W -> WbT [n][k]) --------
__global__ __launch_bounds__(256) void kc_convert(
        const float* __restrict__ h, const float* __restrict__ W,
        u16* __restrict__ hb, u16* __restrict__ WbT)
{
    if (blockIdx.x < 2048) {
        const size_t t = (size_t)blockIdx.x * 256 + threadIdx.x;
        const float4v* src = (const float4v*)h + t * 2;
        const float4v v0 = src[0], v1 = src[1];
        short8v o;
        o[0] = (short)f2bf(v0[0]); o[1] = (short)f2bf(v0[1]);
        o[2] = (short)f2bf(v0[2]); o[3] = (short)f2bf(v0[3]);
        o[4] = (short)f2bf(v1[0]); o[5] = (short)f2bf(v1[1]);
        o[6] = (short)f2bf(v1[2]); o[7] = (short)f2bf(v1[3]);
        *(short8v*)(hb + t * 8) = o;
    } else {
        const int t2 = (blockIdx.x - 2048) * 256 + threadIdx.x;
        const int k = t2 >> 4;
        const int n0 = (t2 & 15) * 8;
        const float4v* src = (const float4v*)(W + (size_t)k * D_OUT + n0);
        const float4v v0 = src[0], v1 = src[1];
        #pragma unroll
        for (int e = 0; e < 4; e++) WbT[(size_t)(n0 + e) * D_IN + k] = f2bf(v0[e]);
        #pragma unroll
        for (int e = 0; e < 4; e++) WbT[(size_t)(n0 + 4 + e) * D_IN + k] = f2bf(v1[e]);
    }
}

// ---------------- Kernel 1M: Wh = h@W via MFMA; WhT bf16 [128][8192]; f1,f2 (x log2e) --------
__global__ __launch_bounds__(256) void k1m_proj(
        const u16* __restrict__ hb, const u16* __restrict__ WbT,
        const float* __restrict__ a, u16* __restrict__ WhT,
        float* __restrict__ f1, float* __restrict__ f2)
{
    __shared__ short As[32 * 136];
    __shared__ short Ws[128 * 136];
    __shared__ float pf1[32][65];
    __shared__ float pf2[32][65];

    const int tid = threadIdx.x;
    const int rowbase = blockIdx.x * 32;
    const int lane = tid & 63, w = tid >> 6;
    const int quad = lane >> 4, m16 = lane & 15;

    float4v acc[2][2];
    #pragma unroll
    for (int mt = 0; mt < 2; mt++)
        #pragma unroll
        for (int nt = 0; nt < 2; nt++) {
            acc[mt][nt][0] = 0.f; acc[mt][nt][1] = 0.f;
            acc[mt][nt][2] = 0.f; acc[mt][nt][3] = 0.f;
        }

    for (int c = 0; c < 4; c++) {
        const int kc0 = c * 128;
        if (c) __syncthreads();
        {
            const int row = tid >> 3, koff = (tid & 7) * 16;
            const short8v* src = (const short8v*)(hb + (size_t)(rowbase + row) * D_IN + kc0 + koff);
            const short8v s0 = src[0], s1 = src[1];
            *(short8v*)&As[row * 136 + koff] = s0;
            *(short8v*)&As[row * 136 + koff + 8] = s1;
        }
        {
            const int n = tid & 127, h2 = tid >> 7;
            #pragma unroll
            for (int i = 0; i < 8; i++) {
                const int koff = h2 * 64 + i * 8;
                *(short8v*)&Ws[n * 136 + koff] =
                    *(const short8v*)(WbT + (size_t)n * D_IN + kc0 + koff);
            }
        }
        __syncthreads();
        #pragma unroll
        for (int ks = 0; ks < 4; ks++) {
            const int ko = ks * 32 + quad * 8;
            const short8v af0 = *(const short8v*)&As[m16 * 136 + ko];
            const short8v af1 = *(const short8v*)&As[(16 + m16) * 136 + ko];
            const short8v bf0 = *(const short8v*)&Ws[(w * 32 + m16) * 136 + ko];
            const short8v bf1 = *(const short8v*)&Ws[(w * 32 + 16 + m16) * 136 + ko];
            acc[0][0] = __builtin_amdgcn_mfma_f32_16x16x32_bf16(af0, bf0, acc[0][0], 0, 0, 0);
            acc[0][1] = __builtin_amdgcn_mfma_f32_16x16x32_bf16(af0, bf1, acc[0][1], 0, 0, 0);
            acc[1][0] = __builtin_amdgcn_mfma_f32_16x16x32_bf16(af1, bf0, acc[1][0], 0, 0, 0);
            acc[1][1] = __builtin_amdgcn_mfma_f32_16x16x32_bf16(af1, bf1, acc[1][1], 0, 0, 0);
        }
    }

    #pragma unroll
    for (int mt = 0; mt < 2; mt++) {
        #pragma unroll
        for (int nt = 0; nt < 2; nt++) {
            const int n = w * 32 + nt * 16 + m16;
            short4v p;
            #pragma unroll
            for (int reg = 0; reg < 4; reg++) p[reg] = (short)f2bf(acc[mt][nt][reg]);
            *(short4v*)(WhT + (size_t)n * N_NODES + rowbase + mt * 16 + quad * 4) = p;
        }
    }

    float a1v[2], a2v[2];
    #pragma unroll
    for (int nt = 0; nt < 2; nt++) {
        a1v[nt] = a[w * 32 + nt * 16 + m16];
        a2v[nt] = a[D_OUT + w * 32 + nt * 16 + m16];
    }
    #pragma unroll
    for (int mt = 0; mt < 2; mt++)
        #pragma unroll
        for (int reg = 0; reg < 4; reg++) {
            const int row = mt * 16 + quad * 4 + reg;
            pf1[row][w * 16 + m16] = acc[mt][0][reg] * a1v[0] + acc[mt][1][reg] * a1v[1];
            pf2[row][w * 16 + m16] = acc[mt][0][reg] * a2v[0] + acc[mt][1][reg] * a2v[1];
        }
    __syncthreads();
    if (tid < 32) {
        float s = 0.f;
        #pragma unroll
        for (int j = 0; j < 64; j++) s += pf1[tid][j];
        f1[rowbase + tid] = s * LOG2E;
    } else if (tid < 64) {
        float s = 0.f;
        #pragma unroll
        for (int j = 0; j < 64; j++) s += pf2[tid - 32][j];
        f2[rowbase + tid - 32] = s * LOG2E;
    }
}

// ---------------- Kernel 2: fused mask+exp2 + partial PV via MFMA ----------------
// 64 rows x 2048-col segment per block (512 blocks). 128-col chunks, dbuf Pt, 1 barrier/chunk.
// Thread (r,g): r=tid>>2 in [0,64), g=tid&3 owns cols [g*32, g*32+32) of each chunk.
// Rationale: adj request bytes = WhT request bytes per chunk (50/50 mix vs 33/67 at 32 rows),
// raising adj's share of the per-CU vector-memory data path.
__global__ __launch_bounds__(256, 2) void k2_attn(
        const int* __restrict__ adj, const u16* __restrict__ WhT,
        const float* __restrict__ f1g, const float* __restrict__ f2g,
        float* __restrict__ numw, float* __restrict__ denw)
{
    __shared__ short Pt[2][ROWS * 136];  // 34.8 KB double-buffered P tile (stride 136 shorts)
    __shared__ float f2s[2304];          // 2048 + 4-float pad per 32 (bank-spread)
    __shared__ float f1s[ROWS];
    __shared__ float rs[ROWS][5];
    __shared__ float ssum[ROWS];

    const int tid = threadIdx.x;
    const int rb  = blockIdx.x >> 2;
    const int seg = blockIdx.x & 3;
    const int rowbase = rb * ROWS;
    const int colbase = seg * SEGCOLS;
    const int r = tid >> 2, g = tid & 3;
    const int lane = tid & 63, w = tid >> 6;
    const int quad = lane >> 4, m16 = lane & 15;

    if (tid < ROWS) f1s[tid] = f1g[rowbase + tid];
    #pragma unroll
    for (int i = 0; i < 2; i++) {
        const int idx = (tid + 256 * i) * 4;
        *(float4v*)&f2s[idx + ((idx >> 5) << 2)] = *(const float4v*)&f2g[colbase + idx];
    }

    const int4v* arow = (const int4v*)(adj + (size_t)(rowbase + r) * N_NODES + colbase);
    int4v a4[8];
    #pragma unroll
    for (int i = 0; i < 8; i++) a4[i] = arow[g * 8 + i];   // chunk 0: cols g*32..+31

    float4v acc[4][2];
    #pragma unroll
    for (int mt = 0; mt < 4; mt++)
        #pragma unroll
        for (int nt = 0; nt < 2; nt++) {
            acc[mt][nt][0] = 0.f; acc[mt][nt][1] = 0.f;
            acc[mt][nt][2] = 0.f; acc[mt][nt][3] = 0.f;
        }
    float ls0 = 0.f, ls1 = 0.f, ls2 = 0.f, ls3 = 0.f;

    __syncthreads();   // f1s/f2s ready

    const float f1v = f1s[r];

    auto weight_phase = [&](int jc, short* ptb) {
        const float* f2p = &f2s[jc * 144 + g * 36];
        u32 packed[16];
        #pragma unroll
        for (int i = 0; i < 8; i++) {
            const float4v fv = *(const float4v*)&f2p[i * 4];
            const int4v av = a4[i];
            u32 wb[4];
            #pragma unroll
            for (int e = 0; e < 4; e++) {
                const u32 msk = (av[e] > 0) ? 0xffff0000u : 0u;
                float x = f1v + fv[e];
                x = fmaxf(x, SLOPEF * x);                            // leaky_relu (log2 domain)
                const float ex = __builtin_amdgcn_exp2f(x);
                const u32 wt = __float_as_uint(ex) & msk;            // masked + bf16-trunc
                wb[e] = wt;
                if (e == 0) ls0 += __uint_as_float(wt);
                else if (e == 1) ls1 += __uint_as_float(wt);
                else if (e == 2) ls2 += __uint_as_float(wt);
                else ls3 += __uint_as_float(wt);
            }
            packed[i * 2]     = __builtin_amdgcn_perm(wb[1], wb[0], 0x07060302);
            packed[i * 2 + 1] = __builtin_amdgcn_perm(wb[3], wb[2], 0x07060302);
        }
        int* pdst = (int*)(ptb + r * 136 + g * 32);
        #pragma unroll
        for (int q = 0; q < 4; q++) {
            int4v st;
            st[0] = (int)packed[q * 4 + 0]; st[1] = (int)packed[q * 4 + 1];
            st[2] = (int)packed[q * 4 + 2]; st[3] = (int)packed[q * 4 + 3];
            *(int4v*)&pdst[q * 4] = st;
        }
    };

    // prologue: weight(0) into buf0, then prefetch chunk 1
    weight_phase(0, Pt[0]);
    #pragma unroll
    for (int i = 0; i < 8; i++) a4[i] = arow[32 + g * 8 + i];

    #pragma unroll 2
    for (int jc = 0; jc < NCHUNK; jc++) {
        lds_barrier();   // Pt[jc&1] complete; Pt[(jc+1)&1] free

        // ---- MFMA: acc += P[64 x 128] @ Wh[128 x 128] (this wave's 32 feature cols) ----
        {
            const u16* b0p = WhT + (size_t)(w * 32 + m16) * N_NODES + colbase + jc * 128 + quad * 8;
            const u16* b1p = b0p + 16 * N_NODES;
            const short* ap = &Pt[jc & 1][m16 * 136 + quad * 8];
            #pragma unroll
            for (int ks = 0; ks < 4; ks++) {
                const int ko = ks * 32;
                const short8v bv0 = *(const short8v*)(b0p + ko);
                const short8v bv1 = *(const short8v*)(b1p + ko);
                #pragma unroll
                for (int mt = 0; mt < 4; mt++) {
                    const short8v af = *(const short8v*)(ap + mt * 16 * 136 + ko);
                    acc[mt][0] = __builtin_amdgcn_mfma_f32_16x16x32_bf16(af, bv0, acc[mt][0], 0, 0, 0);
                    acc[mt][1] = __builtin_amdgcn_mfma_f32_16x16x32_bf16(af, bv1, acc[mt][1], 0, 0, 0);
                }
            }
        }
        // ---- next chunk's weight phase overlaps this chunk's B-load/MFMA latency ----
        if (jc + 1 < NCHUNK) {
            weight_phase(jc + 1, Pt[(jc + 1) & 1]);
            if (jc + 2 < NCHUNK) {
                #pragma unroll
                for (int i = 0; i < 8; i++) a4[i] = arow[(jc + 2) * 32 + g * 8 + i];
            }
        }
    }

    // per-row partial denominator
    rs[r][g] = (ls0 + ls1) + (ls2 + ls3);
    __syncthreads();
    if (tid < ROWS) {
        float s = 0.f;
        #pragma unroll
        for (int j = 0; j < 4; j++) s += rs[tid][j];
        ssum[tid] = s;
        denw[(size_t)(rowbase + tid) * NSEG + seg] = s;
    }
    __syncthreads();

    // epilogue: write partial numerator. C/D layout col=lane&15, row=quad*4+reg
    #pragma unroll
    for (int mt = 0; mt < 4; mt++) {
        #pragma unroll
        for (int nt = 0; nt < 2; nt++) {
            const int cl = w * 32 + nt * 16 + m16;
            #pragma unroll
            for (int reg = 0; reg < 4; reg++) {
                const int rl = mt * 16 + quad * 4 + reg;
                numw[((size_t)(rowbase + rl) * NSEG + seg) * D_OUT + cl] = acc[mt][nt][reg];
            }
        }
    }
}

// ---------------- Kernel 3: reduce partials, divide, write output ----------------
__global__ __launch_bounds__(256) void k3_reduce(
        const float* __restrict__ numw, const float* __restrict__ denw,
        float* __restrict__ out)
{
    const int tid = threadIdx.x;
    const int row = blockIdx.x * 2 + (tid >> 7);
    const int c   = tid & 127;
    float s = 0.f, d = 0.f;
    #pragma unroll
    for (int sg = 0; sg < NSEG; sg++) {
        s += numw[((size_t)row * NSEG + sg) * D_OUT + c];
        d += denw[(size_t)row * NSEG + sg];
    }
    out[(size_t)row * D_OUT + c] = s / d;
}

extern "C" void kernel_launch(void* const* d_in, const int* in_sizes, int n_in,
                              void* d_out, int out_size, void* d_ws, size_t ws_size,
                              hipStream_t stream) {
    const float* h   = (const float*)d_in[0];
    const int*   adj = (const int*)d_in[1];
    const float* W   = (const float*)d_in[2];
    const float* a   = (const float*)d_in[3];

    char* ws = (char*)d_ws;
    u16*   hb   = (u16*)ws;                                    // 8 MB
    u16*   WbT  = (u16*)(ws + (size_t)8 * 1024 * 1024);        // 128 KB
    u16*   WhT  = (u16*)(ws + (size_t)9 * 1024 * 1024);        // 2 MB
    float* f1   = (float*)(ws + (size_t)11 * 1024 * 1024);     // 32 KB
    float* f2   = f1 + N_NODES;                                // 32 KB
    float* numw = (float*)(ws + (size_t)12 * 1024 * 1024);     // 16 MB
    float* denw = (float*)(ws + (size_t)28 * 1024 * 1024);     // 128 KB

    kc_convert<<<2080, 256, 0, stream>>>(h, W, hb, WbT);
    k1m_proj<<<N_NODES / 32, 256, 0, stream>>>(hb, WbT, a, WhT, f1, f2);
    k2_attn<<<(N_NODES / ROWS) * NSEG, 256, 0, stream>>>(adj, WhT, f1, f2, numw, denw);
    k3_reduce<<<N_NODES / 2, 256, 0, stream>>>(numw, denw, (float*)d_out);
}